// Round 2
// baseline (257.658 us; speedup 1.0000x reference)
//
#include <hip/hip_runtime.h>

// LSTM fused kernel for MI355X (gfx950).
// B=4096, S=256, H=64, input dim 4 (from Linear(1->4)+tanh).
// grid=256 blocks (1/CU), block=256 threads (4 waves), TB=16 batch rows/block.
// Recurrent matmul via split-bf16 MFMA (3-term hi/lo), gx + bias exact in fp32 VALU.

typedef __attribute__((ext_vector_type(8))) __bf16 bf16x8;
typedef __attribute__((ext_vector_type(4))) float f32x4;

#define S_LEN 256
#define HID 64
#define TB 16
#define CHUNK 64
#define LOG2E 1.4426950408889634f

#if defined(__has_builtin) && __has_builtin(__builtin_amdgcn_exp2f)
#define EXP2F(x) __builtin_amdgcn_exp2f(x)
#else
#define EXP2F(x) exp2f(x)
#endif
#if defined(__has_builtin) && __has_builtin(__builtin_amdgcn_rcpf)
#define RCPF(x) __builtin_amdgcn_rcpf(x)
#else
#define RCPF(x) (1.0f / (x))
#endif

__device__ __forceinline__ float fast_sigmoid(float x) {
    float e = EXP2F(-LOG2E * x);
    return RCPF(1.0f + e);
}
__device__ __forceinline__ float fast_tanh(float x) {
    // tanh(x) = 1 - 2/(exp2(2*log2e*x)+1); saturates correctly for |x| large.
    float e = EXP2F(2.0f * LOG2E * x);
    return 1.0f - 2.0f * RCPF(e + 1.0f);
}

__global__ __launch_bounds__(256, 1)
void lstm_fused(const float* __restrict__ x,
                const float* __restrict__ W1, const float* __restrict__ b1,
                const float* __restrict__ W_ih, const float* __restrict__ W_hh,
                const float* __restrict__ b_ih, const float* __restrict__ b_hh,
                const float* __restrict__ W2, const float* __restrict__ b2,
                float* __restrict__ out)
{
    // fc1 chunk: [t_local][batch_row][4]  (16 KB)
    __shared__ float fc1c[CHUNK][TB][4];
    // h double buffer, split hi/lo, k-grouped for MFMA A-frag b128 reads:
    // [buf][hi/lo][kstep(k>>5)][kg((k>>3)&3)][row][j(k&7)]   (8 KB)
    __shared__ __bf16 hbuf[2][2][2][4][TB][8];
    // final h for output projection: [unit][row]  (4 KB)
    __shared__ float hfin[HID][TB];

    const int tid  = threadIdx.x;
    const int lane = tid & 63;
    const int wv   = tid >> 6;     // wave 0..3
    const int col  = lane & 15;    // N-col within 16-tile / A-row for loads
    const int kg   = lane >> 4;    // k-group 0..3
    const int b0   = blockIdx.x * TB;

    // ---- W_hh B-fragments (hi/lo), resident in VGPRs for all steps ----
    // wave wv owns N-tiles {wv, wv+4, wv+8, wv+12} -> lane's 4 gate rows share unit u=16*wv+col
    bf16x8 whh_h[4][2], whh_l[4][2];
    float  wihv[4][4];   // W_ih rows for gx (exact fp32 path)
    float  biasv[4];     // b_ih + b_hh
    #pragma unroll
    for (int n = 0; n < 4; ++n) {
        const int g = 16 * (wv + 4 * n) + col;
        #pragma unroll
        for (int ks = 0; ks < 2; ++ks) {
            const float* wp = &W_hh[g * 64 + ks * 32 + kg * 8];
            #pragma unroll
            for (int j = 0; j < 8; ++j) {
                float wf  = wp[j];
                __bf16 hi = (__bf16)wf;
                whh_h[n][ks][j] = hi;
                whh_l[n][ks][j] = (__bf16)(wf - (float)hi);
            }
        }
        #pragma unroll
        for (int j = 0; j < 4; ++j) wihv[n][j] = W_ih[g * 4 + j];
        biasv[n] = b_ih[g] + b_hh[g];
    }

    // zero h0 (buffer 0): first 2048 elements of hbuf, 8 per thread
    {
        __bf16* p = &hbuf[0][0][0][0][0][0];
        #pragma unroll
        for (int j = 0; j < 8; ++j) p[tid * 8 + j] = (__bf16)0.0f;
    }

    float w1r[4], b1r[4];
    #pragma unroll
    for (int j = 0; j < 4; ++j) { w1r[j] = W1[j]; b1r[j] = b1[j]; }

    f32x4 cst = {0.f, 0.f, 0.f, 0.f};   // c for (row=kg*4+r, unit u)
    float hlast[4];

    const int u   = 16 * wv + col;       // this lane's h-unit
    const int uks = u >> 5, ukg = (u >> 3) & 3, up = u & 7;

    for (int t = 0; t < S_LEN; ++t) {
        if ((t & (CHUNK - 1)) == 0) {
            __syncthreads();   // prior chunk reads done (covers t=0 zero-init too)
            const int rr = tid & 15;
            const int tq = tid >> 4;     // 0..15, 4 steps each
            f32x4 xv = *(const f32x4*)&x[(b0 + rr) * S_LEN + t + tq * 4];
            #pragma unroll
            for (int tl = 0; tl < 4; ++tl) {
                #pragma unroll
                for (int j = 0; j < 4; ++j)
                    fc1c[tq * 4 + tl][rr][j] = fast_tanh(xv[tl] * w1r[j] + b1r[j]);
            }
            __syncthreads();
        }
        const int cur = t & 1, nxt = cur ^ 1;

        // A fragments: h hi/lo, 2 k-steps (row = col = lane&15, kg = lane>>4)
        bf16x8 ah0 = *(const bf16x8*)&hbuf[cur][0][0][kg][col][0];
        bf16x8 ah1 = *(const bf16x8*)&hbuf[cur][0][1][kg][col][0];
        bf16x8 al0 = *(const bf16x8*)&hbuf[cur][1][0][kg][col][0];
        bf16x8 al1 = *(const bf16x8*)&hbuf[cur][1][1][kg][col][0];

        // 24 MFMAs: 4 N-tiles x (2 k-steps x 3 split terms)
        f32x4 acc[4];
        #pragma unroll
        for (int n = 0; n < 4; ++n) {
            f32x4 a = {0.f, 0.f, 0.f, 0.f};
            a = __builtin_amdgcn_mfma_f32_16x16x32_bf16(ah0, whh_h[n][0], a, 0, 0, 0);
            a = __builtin_amdgcn_mfma_f32_16x16x32_bf16(ah1, whh_h[n][1], a, 0, 0, 0);
            a = __builtin_amdgcn_mfma_f32_16x16x32_bf16(al0, whh_h[n][0], a, 0, 0, 0);
            a = __builtin_amdgcn_mfma_f32_16x16x32_bf16(al1, whh_h[n][1], a, 0, 0, 0);
            a = __builtin_amdgcn_mfma_f32_16x16x32_bf16(ah0, whh_l[n][0], a, 0, 0, 0);
            a = __builtin_amdgcn_mfma_f32_16x16x32_bf16(ah1, whh_l[n][1], a, 0, 0, 0);
            acc[n] = a;
        }

        // gx + bias in exact fp32 (overlaps the in-flight MFMAs on the VALU pipe)
        float gxv[4][4];   // [n][r]
        #pragma unroll
        for (int r = 0; r < 4; ++r) {
            f32x4 fv = *(const f32x4*)&fc1c[t & (CHUNK - 1)][kg * 4 + r][0]; // broadcast read
            #pragma unroll
            for (int n = 0; n < 4; ++n) {
                float s = biasv[n];
                s = fmaf(fv[0], wihv[n][0], s);
                s = fmaf(fv[1], wihv[n][1], s);
                s = fmaf(fv[2], wihv[n][2], s);
                s = fmaf(fv[3], wihv[n][3], s);
                gxv[n][r] = s;
            }
        }

        // elementwise LSTM update (lane-local: all 4 gates of unit u, rows kg*4+r)
        #pragma unroll
        for (int r = 0; r < 4; ++r) {
            float iv = fast_sigmoid(acc[0][r] + gxv[0][r]);
            float fg = fast_sigmoid(acc[1][r] + gxv[1][r]);
            float gv = fast_tanh   (acc[2][r] + gxv[2][r]);
            float ov = fast_sigmoid(acc[3][r] + gxv[3][r]);
            float cv = fg * cst[r] + iv * gv;
            cst[r] = cv;
            float hv = ov * fast_tanh(cv);
            hlast[r] = hv;
            __bf16 hi = (__bf16)hv;
            __bf16 lo = (__bf16)(hv - (float)hi);
            const int rw = kg * 4 + r;    // D row = (lane>>4)*4 + reg  [HW-verified]
            hbuf[nxt][0][uks][ukg][rw][up] = hi;
            hbuf[nxt][1][uks][ukg][rw][up] = lo;
        }
        __syncthreads();
    }

    // epilogue: out[b] = h_last . W2 + b2
    #pragma unroll
    for (int r = 0; r < 4; ++r) hfin[u][kg * 4 + r] = hlast[r];
    __syncthreads();
    if (tid < TB) {
        float s = b2[0];
        #pragma unroll
        for (int uu = 0; uu < HID; ++uu) s += hfin[uu][tid] * W2[uu];
        out[b0 + tid] = s;
    }
}

extern "C" void kernel_launch(void* const* d_in, const int* in_sizes, int n_in,
                              void* d_out, int out_size, void* d_ws, size_t ws_size,
                              hipStream_t stream) {
    (void)in_sizes; (void)n_in; (void)d_ws; (void)ws_size; (void)out_size;
    const float* x    = (const float*)d_in[0];
    const float* W1   = (const float*)d_in[1];
    const float* b1   = (const float*)d_in[2];
    const float* W_ih = (const float*)d_in[3];
    const float* W_hh = (const float*)d_in[4];
    const float* b_ih = (const float*)d_in[5];
    const float* b_hh = (const float*)d_in[6];
    const float* W2   = (const float*)d_in[7];
    const float* b2   = (const float*)d_in[8];
    float* out = (float*)d_out;
    lstm_fused<<<256, 256, 0, stream>>>(x, W1, b1, W_ih, W_hh, b_ih, b_hh, W2, b2, out);
}